// Round 1
// 258.290 us; speedup vs baseline: 1.0435x; 1.0435x over previous
//
#include <hip/hip_runtime.h>
#include <hip/hip_bf16.h>
#include <stdint.h>

#define N_NODES 100000
#define N_EDGES 600000
#define D 128
#define EPS 1e-5f
#define SCAN_BS 512
#define ROW_MASK 0x1FFFF

#define PREP_BLOCKS 321            // (82048+255)/256
#define HIST_BLOCKS 2344           // (N_EDGES+255)/256, 256-thread histogram blocks (K1)
#define XF_BLOCKS   3125           // N_NODES/32, 64-thread 1-wave xform blocks (K3)
#define SC_BLOCKS   9375           // (N_EDGES+63)/64, 64-thread scatter blocks (K3)
#define UPD_BLOCKS  3125           // N_NODES/32, 64-thread 1-wave blocks (K4)

typedef __attribute__((ext_vector_type(8))) short short8;
typedef __attribute__((ext_vector_type(16))) float floatx16;

// ---------- helpers ----------

__device__ __forceinline__ uint32_t pack_bf16_rne(float lo, float hi) {
    uint32_t ul = __builtin_bit_cast(uint32_t, lo);
    uint32_t uh = __builtin_bit_cast(uint32_t, hi);
    ul += 0x7fffu + ((ul >> 16) & 1u);
    uh += 0x7fffu + ((uh >> 16) & 1u);
    return (ul >> 16) | (uh & 0xffff0000u);
}

__device__ __forceinline__ unsigned short f32_to_bf16_rne(float f) {
    uint32_t u = __builtin_bit_cast(uint32_t, f);
    u += 0x7fffu + ((u >> 16) & 1u);
    return (unsigned short)(u >> 16);
}

__device__ __forceinline__ float bflo(uint32_t a) { return __builtin_bit_cast(float, a << 16); }
__device__ __forceinline__ float bfhi(uint32_t a) { return __builtin_bit_cast(float, a & 0xffff0000u); }

// ---------- K1: fused weight preprocessing + destination histogram (+rank) ----------
__global__ void prep_hist(const float* __restrict__ w_m1, const float* __restrict__ w_u1,
                          const float* __restrict__ w_u2, const float* __restrict__ w_m2,
                          const float* __restrict__ b_m2,
                          unsigned short* __restrict__ wm1f, unsigned short* __restrict__ wu1tf,
                          unsigned short* __restrict__ wu2f, unsigned short* __restrict__ wcf,
                          float* __restrict__ vb,
                          const int* __restrict__ col, int* __restrict__ count,
                          int* __restrict__ rank) {
    if (blockIdx.x >= PREP_BLOCKS) {
        int e = (blockIdx.x - PREP_BLOCKS) * 256 + threadIdx.x;
        // rank harvested from the histogram atomic: gives each edge a unique
        // slot within its destination node -> K3 scatter needs no atomics.
        if (e < N_EDGES) rank[e] = atomicAdd(&count[col[e]], 1);
        return;
    }
    int idx = blockIdx.x * 256 + threadIdx.x;
    if (idx < 32768) {
        int j = idx & 7, lane = (idx >> 3) & 63, t = (idx >> 9) & 3, s = idx >> 11;
        int kk = s * 16 + ((lane >> 5) << 3) + j;
        wm1f[idx] = f32_to_bf16_rne(w_m1[kk * 128 + t * 32 + (lane & 31)]);
    } else if (idx < 49152) {
        int ii = idx - 32768;
        int j = ii & 7, lane = (ii >> 3) & 63, t = (ii >> 9) & 3, s = ii >> 11;
        int kk = s * 16 + ((lane >> 5) << 3) + j;
        wu1tf[ii] = f32_to_bf16_rne(w_u1[kk * 128 + t * 32 + (lane & 31)]);
    } else if (idx < 65536) {
        int ii = idx - 49152;
        int j = ii & 7, lane = (ii >> 3) & 63, t = (ii >> 9) & 3, s = ii >> 11;
        int kk = s * 16 + ((lane >> 5) << 3) + j;
        wu2f[ii] = f32_to_bf16_rne(w_u2[kk * 128 + t * 32 + (lane & 31)]);
    } else if (idx < 81920) {
        int ii = idx - 65536;
        int j = ii & 7, lane = (ii >> 3) & 63, t = (ii >> 9) & 3, s = ii >> 11;
        int kk = s * 16 + ((lane >> 5) << 3) + j;
        int nn = t * 32 + (lane & 31);
        float acc = 0.0f;
        for (int q = 0; q < 128; ++q)
            acc += w_m2[kk * 128 + q] * w_u1[(128 + q) * 128 + nn];
        wcf[ii] = f32_to_bf16_rne(acc);
    } else if (idx < 82048) {
        int nn = idx - 81920;
        float acc = 0.0f;
        for (int q = 0; q < 128; ++q)
            acc += b_m2[q] * w_u1[(128 + q) * 128 + nn];
        vb[nn] = acc;
    }
}

// ---------- K2: single-kernel scan (block base via atomic cursor; slice order irrelevant,
// but nodes within one 512-node scan block stay contiguous & ascending -> any 32-node
// group's CSR range is contiguous).
__global__ void scan_one(const int* __restrict__ count, int* __restrict__ base,
                         int* __restrict__ gcur) {
    __shared__ int tmp[SCAN_BS];
    __shared__ int bbase;
    int g = blockIdx.x * SCAN_BS + threadIdx.x;
    int v = (g < N_NODES) ? count[g] : 0;
    tmp[threadIdx.x] = v;
    __syncthreads();
    int acc = v;
#pragma unroll
    for (int off = 1; off < SCAN_BS; off <<= 1) {
        int add = (threadIdx.x >= off) ? tmp[threadIdx.x - off] : 0;
        __syncthreads();
        acc += add;
        tmp[threadIdx.x] = acc;
        __syncthreads();
    }
    if (threadIdx.x == SCAN_BS - 1) bbase = atomicAdd(gcur, acc);
    __syncthreads();
    if (g < N_NODES) base[g] = bbase + acc - v;
}

// ---------- K3: fused xform (XT|XB+b1 bf16 [node][256]) + atomic-free edge scatter ----------
// 1-wave (64-thread) blocks: kernel is wave-private, finer blocks pack/balance better.
__launch_bounds__(64, 4)
__global__ void xform_scatter(const float* __restrict__ x, const short8* __restrict__ w1f,
                              const float* __restrict__ b1, unsigned short* __restrict__ xtb,
                              const int* __restrict__ row, const int* __restrict__ col,
                              const int* __restrict__ rank, const int* __restrict__ base,
                              int* __restrict__ srow) {
    if (blockIdx.x >= XF_BLOCKS) {
        int e = (blockIdx.x - XF_BLOCKS) * 64 + threadIdx.x;
        if (e < N_EDGES) {
            int c = col[e];
            int p = base[c] + rank[e];          // no atomic round-trip
            srow[p] = row[e] | ((c & 31) << 17);   // row (17b) | node-in-group (5b)
        }
        return;
    }

    __shared__ __align__(16) short h1[32 * 136];
    const int lane = threadIdx.x;
    const int l31  = lane & 31;
    const int half = lane >> 5;
    short* hl = h1;

    const int nbase = blockIdx.x * 32;          // 3125*32 == N_NODES exactly
    const int n = nbase + l31;
    const float* px = x + (size_t)n * D + half * 8;

    union { short8 v; uint32_t u[4]; } fa[8];
#pragma unroll
    for (int s = 0; s < 8; ++s) {
        const int off = s * 16;
        float4 a0 = *(const float4*)(px + off);
        float4 a1 = *(const float4*)(px + off + 4);
        fa[s].u[0] = pack_bf16_rne(a0.x, a0.y); fa[s].u[1] = pack_bf16_rne(a0.z, a0.w);
        fa[s].u[2] = pack_bf16_rne(a1.x, a1.y); fa[s].u[3] = pack_bf16_rne(a1.z, a1.w);
    }

#pragma unroll
    for (int p = 0; p < 2; ++p) {
        floatx16 acc[4];
#pragma unroll
        for (int t = 0; t < 4; ++t) acc[t] = (floatx16)0.0f;
#pragma unroll
        for (int s = 0; s < 8; ++s) {
#pragma unroll
            for (int t = 0; t < 4; ++t) {
                short8 wf = w1f[((p * 8 + s) * 4 + t) * 64 + lane];
                acc[t] = __builtin_amdgcn_mfma_f32_32x32x16_bf16(fa[s].v, wf, acc[t], 0, 0, 0);
            }
        }
#pragma unroll
        for (int t = 0; t < 4; ++t) {
            float bias = p ? b1[t * 32 + l31] : 0.0f;
#pragma unroll
            for (int r = 0; r < 16; ++r) {
                int m = (r & 3) + 8 * (r >> 2) + 4 * half;
                hl[m * 136 + t * 32 + l31] = (short)f32_to_bf16_rne(acc[t][r] + bias);
            }
        }
#pragma unroll
        for (int it = 0; it < 8; ++it) {
            int off = it * 512 + lane * 8;
            int r2 = off >> 7;
            int c2 = off & 127;
            short8 v = *(const short8*)(hl + r2 * 136 + c2);
            *(short8*)(xtb + (size_t)(nbase + r2) * 256 + p * 128 + c2) = v;
        }
    }
}

// ---------- K4: fused aggregation + update ----------
// 1-wave (64-thread) blocks, 32 nodes each. Phase A: 8-edge gather groups (16 loads
// in flight), run-merge, bf16 flush to LDS. Phase B: GEMMs + LN + residual.
__launch_bounds__(64, 4)
__global__ void upd_kernel(const float* __restrict__ x, const uint32_t* __restrict__ xtb32,
                           const int* __restrict__ srowpk,
                           const int* __restrict__ base, const int* __restrict__ count,
                           const short8* __restrict__ wu1tf, const short8* __restrict__ wcf,
                           const short8* __restrict__ wu2f,
                           const float* __restrict__ b_u1, const float* __restrict__ vb,
                           const float* __restrict__ b_u2,
                           const float* __restrict__ gamma, const float* __restrict__ beta,
                           float* __restrict__ out) {
    __shared__ __align__(16) short h1[32 * 136];
    const int lane = threadIdx.x;
    const int l31  = lane & 31;
    const int half = lane >> 5;
    short* hl = h1;
    uint32_t* accu = (uint32_t*)hl;            // phase-A hsum: [32 nodes][64 dwords] = 8 KB

    const int nbase = blockIdx.x * 32;
    const int nc = nbase + l31;

    // per-row CSR info (lane-parallel), group range via shuffle
    const int b_l = base[nc];
    const int c_l = count[nc];
    const int ebeg = __shfl(b_l, 0);
    const int eend = __shfl(b_l, 31) + __shfl(c_l, 31);
    const float dgv = (float)c_l;

    // zero hsum rows (deg-0 nodes never flushed)
#pragma unroll
    for (int i = 0; i < 32; ++i) accu[i * 64 + lane] = 0;

    // ---- Phase A: edge stream, run-merged, 8-deep gather groups ----
    {
        float s_lo = 0.0f, s_hi = 0.0f;
        int curnib = -1;
        for (int t0 = ebeg; t0 < eend; t0 += 64) {
            const int nb = min(64, eend - t0);
            int pk = (lane < nb) ? srowpk[t0 + lane] : 0;
            for (int d = 0; d < nb; d += 8) {
                uint32_t av[8], bv[8];
                int nn[8];
#pragma unroll
                for (int k = 0; k < 8; ++k) {
                    int p = __shfl(pk, min(d + k, nb - 1));
                    int r = p & ROW_MASK;
                    nn[k] = p >> 17;
                    av[k] = xtb32[(size_t)r * 128 + lane];
                    bv[k] = xtb32[(size_t)(nbase + nn[k]) * 128 + 64 + lane];
                }
#pragma unroll
                for (int k = 0; k < 8; ++k) {
                    if (d + k < nb) {
                        float vlo = fmaxf(bflo(av[k]) + bflo(bv[k]), 0.0f);
                        float vhi = fmaxf(bfhi(av[k]) + bfhi(bv[k]), 0.0f);
                        if (nn[k] != curnib) {
                            if (curnib >= 0) accu[curnib * 64 + lane] = pack_bf16_rne(s_lo, s_hi);
                            curnib = nn[k]; s_lo = vlo; s_hi = vhi;
                        } else { s_lo += vlo; s_hi += vhi; }
                    }
                }
            }
        }
        if (curnib >= 0) accu[curnib * 64 + lane] = pack_bf16_rne(s_lo, s_hi);
    }

    // ---- Phase B: GEMMs + LN (wave-private LDS; per-wave DS ordering suffices) ----
    const float* px = x + (size_t)nc * D + half * 8;

    floatx16 acc[4];
#pragma unroll
    for (int t = 0; t < 4; ++t) acc[t] = (floatx16)0.0f;

#pragma unroll
    for (int s = 0; s < 16; ++s) {
        union { short8 v; uint32_t u[4]; } fa;
        const short8* bf;
        if (s < 8) {
            const int off = s * 16;
            float4 a0 = *(const float4*)(px + off);
            float4 a1 = *(const float4*)(px + off + 4);
            fa.u[0] = pack_bf16_rne(a0.x, a0.y); fa.u[1] = pack_bf16_rne(a0.z, a0.w);
            fa.u[2] = pack_bf16_rne(a1.x, a1.y); fa.u[3] = pack_bf16_rne(a1.z, a1.w);
            bf = wu1tf + (s * 4) * 64;
        } else {
            fa.v = *(const short8*)((const short*)accu + l31 * 128 + (s - 8) * 16 + half * 8);
            bf = wcf + ((s - 8) * 4) * 64;
        }
#pragma unroll
        for (int t = 0; t < 4; ++t) {
            short8 wf = bf[t * 64 + lane];
            acc[t] = __builtin_amdgcn_mfma_f32_32x32x16_bf16(fa.v, wf, acc[t], 0, 0, 0);
        }
    }

    float bu1[4], vbt[4];
#pragma unroll
    for (int t = 0; t < 4; ++t) {
        bu1[t] = b_u1[t * 32 + l31];
        vbt[t] = vb[t * 32 + l31];
    }

#pragma unroll
    for (int r = 0; r < 16; ++r) {
        int m = (r & 3) + 8 * (r >> 2) + 4 * half;
        float dg = __shfl(dgv, m, 32);
#pragma unroll
        for (int t = 0; t < 4; ++t) {
            float v = fmaxf(acc[t][r] + bu1[t] + dg * vbt[t], 0.0f);
            hl[m * 136 + t * 32 + l31] = (short)f32_to_bf16_rne(v);
        }
    }

    floatx16 acc2[4];
#pragma unroll
    for (int t = 0; t < 4; ++t) acc2[t] = (floatx16)0.0f;

#pragma unroll
    for (int s = 0; s < 8; ++s) {
        short8 af = *(const short8*)(hl + l31 * 136 + s * 16 + half * 8);
#pragma unroll
        for (int t = 0; t < 4; ++t) {
            short8 wf = wu2f[(s * 4 + t) * 64 + lane];
            acc2[t] = __builtin_amdgcn_mfma_f32_32x32x16_bf16(af, wf, acc2[t], 0, 0, 0);
        }
    }

    float g4[4], be4[4], bias2[4];
#pragma unroll
    for (int t = 0; t < 4; ++t) {
        g4[t]    = gamma[t * 32 + l31];
        be4[t]   = beta[t * 32 + l31];
        bias2[t] = b_u2[t * 32 + l31];
    }

    // LN epilogue via LDS (fp32, two 16-row passes reusing hl) -> float4 stores.
    float* hf = (float*)hl;
#pragma unroll
    for (int p = 0; p < 2; ++p) {
#pragma unroll
        for (int rr = 0; rr < 8; ++rr) {
            int r = p * 8 + rr;
            float hv[4];
            float s1 = 0.0f, s2 = 0.0f;
#pragma unroll
            for (int t = 0; t < 4; ++t) {
                hv[t] = acc2[t][r] + bias2[t];
                s1 += hv[t];
                s2 += hv[t] * hv[t];
            }
#pragma unroll
            for (int mask = 1; mask < 32; mask <<= 1) {
                s1 += __shfl_xor(s1, mask);
                s2 += __shfl_xor(s2, mask);
            }
            float mean = s1 * (1.0f / 128.0f);
            float var  = s2 * (1.0f / 128.0f) - mean * mean;
            float rs   = rsqrtf(var + EPS);
            int m = (r & 3) + 8 * (r >> 2) + 4 * half;
            int mrow = m - 16 * p;
#pragma unroll
            for (int t = 0; t < 4; ++t)
                hf[mrow * 132 + t * 32 + l31] = (hv[t] - mean) * rs * g4[t] + be4[t];
        }
#pragma unroll
        for (int it = 0; it < 8; ++it) {
            int q = it * 64 + lane;
            int r2 = q >> 5;
            int c4 = q & 31;
            int node = nbase + 16 * p + r2;
            float4 v = *(const float4*)(hf + r2 * 132 + c4 * 4);
            float4 xr = *(const float4*)(x + (size_t)node * D + c4 * 4);
            v.x += xr.x; v.y += xr.y; v.z += xr.z; v.w += xr.w;
            *(float4*)(out + (size_t)node * D + c4 * 4) = v;
        }
    }
}

// ---------- launch ----------
extern "C" void kernel_launch(void* const* d_in, const int* in_sizes, int n_in,
                              void* d_out, int out_size, void* d_ws, size_t ws_size,
                              hipStream_t stream) {
    const float* x     = (const float*)d_in[0];
    const int*   edge  = (const int*)d_in[1];
    const float* w_m1  = (const float*)d_in[2];
    const float* b_m1  = (const float*)d_in[3];
    const float* w_m2  = (const float*)d_in[4];
    const float* b_m2  = (const float*)d_in[5];
    const float* w_u1  = (const float*)d_in[6];
    const float* b_u1  = (const float*)d_in[7];
    const float* w_u2  = (const float*)d_in[8];
    const float* b_u2  = (const float*)d_in[9];
    const float* gamma = (const float*)d_in[10];
    const float* beta  = (const float*)d_in[11];
    float* out = (float*)d_out;

    char* ws = (char*)d_ws;
    size_t off = 0;
    auto alloc = [&](size_t bytes) { void* p = ws + off; off = (off + bytes + 15) & ~(size_t)15; return p; };

    unsigned short* xtb   = (unsigned short*)alloc((size_t)N_NODES * 256 * 2);  // XT | XB+b1
    unsigned short* wm1f  = (unsigned short*)alloc(256 * 128 * 2);
    unsigned short* wu1tf = (unsigned short*)alloc(128 * 128 * 2);
    unsigned short* wcf   = (unsigned short*)alloc(128 * 128 * 2);
    unsigned short* wu2f  = (unsigned short*)alloc(128 * 128 * 2);
    float* vb    = (float*)alloc(128 * 4);
    int* count   = (int*)alloc((size_t)N_NODES * 4 + 16);   // + gcur tail
    int* gcur    = count + N_NODES;
    int* base    = (int*)alloc((size_t)N_NODES * 4);
    int* rank    = (int*)alloc((size_t)N_EDGES * 4);
    int* srow    = (int*)alloc((size_t)N_EDGES * 4);

    const int* rowi = edge;            // edge_index[0]
    const int* coli = edge + N_EDGES;  // edge_index[1]
    const int NB = (N_NODES + SCAN_BS - 1) / SCAN_BS;  // 196 blocks

    (void)hipMemsetAsync(count, 0, (size_t)N_NODES * 4 + 16, stream);  // count + gcur

    // K1: all weight prep + destination histogram (+rank harvest)
    prep_hist<<<PREP_BLOCKS + HIST_BLOCKS, 256, 0, stream>>>(
        w_m1, w_u1, w_u2, w_m2, b_m2, wm1f, wu1tf, wu2f, wcf, vb, coli, count, rank);

    // K2: single-kernel scan
    scan_one<<<NB, SCAN_BS, 0, stream>>>(count, base, gcur);

    // K3: xform + atomic-free packed edge scatter fused (1-wave blocks)
    xform_scatter<<<XF_BLOCKS + SC_BLOCKS, 64, 0, stream>>>(
        x, (const short8*)wm1f, b_m1, xtb, rowi, coli, rank, base, srow);

    // K4: fused aggregation + update (1-wave blocks)
    upd_kernel<<<UPD_BLOCKS, 64, 0, stream>>>(
        x, (const uint32_t*)xtb, srow, base, count,
        (const short8*)wu1tf, (const short8*)wcf, (const short8*)wu2f,
        b_u1, vb, b_u2, gamma, beta, out);
}

// Round 2
// 256.334 us; speedup vs baseline: 1.0515x; 1.0076x over previous
//
#include <hip/hip_runtime.h>
#include <hip/hip_bf16.h>
#include <stdint.h>

#define N_NODES 100000
#define N_EDGES 600000
#define D 128
#define EPS 1e-5f
#define SCAN_BS 512
#define ROW_MASK 0x1FFFF

#define PREP_BLOCKS 321            // (82048+255)/256
#define HIST_BLOCKS 2344           // (N_EDGES+255)/256, 256-thread histogram blocks (K1)
#define XF_BLOCKS   3125           // N_NODES/32, 64-thread 1-wave xform blocks (K3)
#define SC_BLOCKS   2344           // (N_EDGES/4+63)/64, 64-thread x 4-edge scatter blocks (K3)
#define UPD_BLOCKS  3125           // N_NODES/32, 64-thread 1-wave blocks (K4)

typedef __attribute__((ext_vector_type(8))) short short8;
typedef __attribute__((ext_vector_type(16))) float floatx16;

// ---------- helpers ----------

__device__ __forceinline__ uint32_t pack_bf16_rne(float lo, float hi) {
    uint32_t ul = __builtin_bit_cast(uint32_t, lo);
    uint32_t uh = __builtin_bit_cast(uint32_t, hi);
    ul += 0x7fffu + ((ul >> 16) & 1u);
    uh += 0x7fffu + ((uh >> 16) & 1u);
    return (ul >> 16) | (uh & 0xffff0000u);
}

__device__ __forceinline__ unsigned short f32_to_bf16_rne(float f) {
    uint32_t u = __builtin_bit_cast(uint32_t, f);
    u += 0x7fffu + ((u >> 16) & 1u);
    return (unsigned short)(u >> 16);
}

__device__ __forceinline__ float bflo(uint32_t a) { return __builtin_bit_cast(float, a << 16); }
__device__ __forceinline__ float bfhi(uint32_t a) { return __builtin_bit_cast(float, a & 0xffff0000u); }

// ---------- K1: fused weight preprocessing + destination histogram (+rank) ----------
__global__ void prep_hist(const float* __restrict__ w_m1, const float* __restrict__ w_u1,
                          const float* __restrict__ w_u2, const float* __restrict__ w_m2,
                          const float* __restrict__ b_m2,
                          unsigned short* __restrict__ wm1f, unsigned short* __restrict__ wu1tf,
                          unsigned short* __restrict__ wu2f, unsigned short* __restrict__ wcf,
                          float* __restrict__ vb,
                          const int* __restrict__ col, int* __restrict__ count,
                          int* __restrict__ rank) {
    if (blockIdx.x >= PREP_BLOCKS) {
        int e = (blockIdx.x - PREP_BLOCKS) * 256 + threadIdx.x;
        if (e < N_EDGES) rank[e] = atomicAdd(&count[col[e]], 1);
        return;
    }
    int idx = blockIdx.x * 256 + threadIdx.x;
    if (idx < 32768) {
        int j = idx & 7, lane = (idx >> 3) & 63, t = (idx >> 9) & 3, s = idx >> 11;
        int kk = s * 16 + ((lane >> 5) << 3) + j;
        wm1f[idx] = f32_to_bf16_rne(w_m1[kk * 128 + t * 32 + (lane & 31)]);
    } else if (idx < 49152) {
        int ii = idx - 32768;
        int j = ii & 7, lane = (ii >> 3) & 63, t = (ii >> 9) & 3, s = ii >> 11;
        int kk = s * 16 + ((lane >> 5) << 3) + j;
        wu1tf[ii] = f32_to_bf16_rne(w_u1[kk * 128 + t * 32 + (lane & 31)]);
    } else if (idx < 65536) {
        int ii = idx - 49152;
        int j = ii & 7, lane = (ii >> 3) & 63, t = (ii >> 9) & 3, s = ii >> 11;
        int kk = s * 16 + ((lane >> 5) << 3) + j;
        wu2f[ii] = f32_to_bf16_rne(w_u2[kk * 128 + t * 32 + (lane & 31)]);
    } else if (idx < 81920) {
        int ii = idx - 65536;
        int j = ii & 7, lane = (ii >> 3) & 63, t = (ii >> 9) & 3, s = ii >> 11;
        int kk = s * 16 + ((lane >> 5) << 3) + j;
        int nn = t * 32 + (lane & 31);
        float acc = 0.0f;
        for (int q = 0; q < 128; ++q)
            acc += w_m2[kk * 128 + q] * w_u1[(128 + q) * 128 + nn];
        wcf[ii] = f32_to_bf16_rne(acc);
    } else if (idx < 82048) {
        int nn = idx - 81920;
        float acc = 0.0f;
        for (int q = 0; q < 128; ++q)
            acc += b_m2[q] * w_u1[(128 + q) * 128 + nn];
        vb[nn] = acc;
    }
}

// ---------- K2: single-kernel scan ----------
__global__ void scan_one(const int* __restrict__ count, int* __restrict__ base,
                         int* __restrict__ gcur) {
    __shared__ int tmp[SCAN_BS];
    __shared__ int bbase;
    int g = blockIdx.x * SCAN_BS + threadIdx.x;
    int v = (g < N_NODES) ? count[g] : 0;
    tmp[threadIdx.x] = v;
    __syncthreads();
    int acc = v;
#pragma unroll
    for (int off = 1; off < SCAN_BS; off <<= 1) {
        int add = (threadIdx.x >= off) ? tmp[threadIdx.x - off] : 0;
        __syncthreads();
        acc += add;
        tmp[threadIdx.x] = acc;
        __syncthreads();
    }
    if (threadIdx.x == SCAN_BS - 1) bbase = atomicAdd(gcur, acc);
    __syncthreads();
    if (g < N_NODES) base[g] = bbase + acc - v;
}

// ---------- K3: fused xform (XT|XB+b1 bf16 [node][256]) + atomic-free edge scatter ----------
__launch_bounds__(64, 4)
__global__ void xform_scatter(const float* __restrict__ x, const short8* __restrict__ w1f,
                              const float* __restrict__ b1, unsigned short* __restrict__ xtb,
                              const int* __restrict__ row, const int* __restrict__ col,
                              const int* __restrict__ rank, const int* __restrict__ base,
                              int* __restrict__ srow) {
    if (blockIdx.x >= XF_BLOCKS) {
        int e4 = (((blockIdx.x - XF_BLOCKS) * 64 + threadIdx.x) << 2);
        if (e4 < N_EDGES) {
            int4 r4 = *(const int4*)(row + e4);
            int4 c4 = *(const int4*)(col + e4);
            int4 k4 = *(const int4*)(rank + e4);
            srow[base[c4.x] + k4.x] = r4.x | ((c4.x & 31) << 17);
            srow[base[c4.y] + k4.y] = r4.y | ((c4.y & 31) << 17);
            srow[base[c4.z] + k4.z] = r4.z | ((c4.z & 31) << 17);
            srow[base[c4.w] + k4.w] = r4.w | ((c4.w & 31) << 17);
        }
        return;
    }

    __shared__ __align__(16) short h1[32 * 136];
    const int lane = threadIdx.x;
    const int l31  = lane & 31;
    const int half = lane >> 5;
    short* hl = h1;

    const int nbase = blockIdx.x * 32;          // 3125*32 == N_NODES exactly
    const int n = nbase + l31;
    const float* px = x + (size_t)n * D + half * 8;

    union { short8 v; uint32_t u[4]; } fa[8];
#pragma unroll
    for (int s = 0; s < 8; ++s) {
        const int off = s * 16;
        float4 a0 = *(const float4*)(px + off);
        float4 a1 = *(const float4*)(px + off + 4);
        fa[s].u[0] = pack_bf16_rne(a0.x, a0.y); fa[s].u[1] = pack_bf16_rne(a0.z, a0.w);
        fa[s].u[2] = pack_bf16_rne(a1.x, a1.y); fa[s].u[3] = pack_bf16_rne(a1.z, a1.w);
    }

#pragma unroll
    for (int p = 0; p < 2; ++p) {
        floatx16 acc[4];
#pragma unroll
        for (int t = 0; t < 4; ++t) acc[t] = (floatx16)0.0f;
#pragma unroll
        for (int s = 0; s < 8; ++s) {
#pragma unroll
            for (int t = 0; t < 4; ++t) {
                short8 wf = w1f[((p * 8 + s) * 4 + t) * 64 + lane];
                acc[t] = __builtin_amdgcn_mfma_f32_32x32x16_bf16(fa[s].v, wf, acc[t], 0, 0, 0);
            }
        }
#pragma unroll
        for (int t = 0; t < 4; ++t) {
            float bias = p ? b1[t * 32 + l31] : 0.0f;
#pragma unroll
            for (int r = 0; r < 16; ++r) {
                int m = (r & 3) + 8 * (r >> 2) + 4 * half;
                hl[m * 136 + t * 32 + l31] = (short)f32_to_bf16_rne(acc[t][r] + bias);
            }
        }
#pragma unroll
        for (int it = 0; it < 8; ++it) {
            int off = it * 512 + lane * 8;
            int r2 = off >> 7;
            int c2 = off & 127;
            short8 v = *(const short8*)(hl + r2 * 136 + c2);
            *(short8*)(xtb + (size_t)(nbase + r2) * 256 + p * 128 + c2) = v;
        }
    }
}

// ---------- K4: fused aggregation + update ----------
// 1-wave blocks, 32 nodes each. Phase A: quarter-wave edge streams — each 16-lane
// quarter owns 8 nodes' contiguous CSR slice (disjoint destinations, no flush races).
// XB rows (block's own 32 nodes) prestaged in LDS; XT gathered as dwordx4/lane
// (4 edges per wave-load), 16 loads batched per chunk for deep MLP.
__launch_bounds__(64, 2)
__global__ void upd_kernel(const float* __restrict__ x, const uint32_t* __restrict__ xtb32,
                           const int* __restrict__ srowpk,
                           const int* __restrict__ base, const int* __restrict__ count,
                           const short8* __restrict__ wu1tf, const short8* __restrict__ wcf,
                           const short8* __restrict__ wu2f,
                           const float* __restrict__ b_u1, const float* __restrict__ vb,
                           const float* __restrict__ b_u2,
                           const float* __restrict__ gamma, const float* __restrict__ beta,
                           float* __restrict__ out) {
    __shared__ __align__(16) short h1[32 * 136];          // accu (phase A) / h + LN (phase B)
    __shared__ __align__(16) uint32_t XBlds[32 * 64];     // 32 XB rows, 8 KB
    const int lane = threadIdx.x;
    const int l31  = lane & 31;
    const int half = lane >> 5;
    const int t    = lane & 15;          // lane within quarter
    const int q16  = lane & 48;          // quarter * 16
    short* hl = h1;
    uint32_t* accu = (uint32_t*)hl;      // [32 nodes][64 dwords] bf16-packed

    const int nbase = blockIdx.x * 32;
    const int nc = nbase + l31;

    // per-node CSR info (lane-parallel)
    const int b_l = base[nc];
    const int c_l = count[nc];
    const float dgv = (float)c_l;

    // quarter q owns nodes [8q, 8q+8): contiguous CSR slice
    const int qsrc = q16 >> 1;                           // 8*q
    const int qbeg = __shfl(b_l, qsrc);
    const int qend = __shfl(b_l, qsrc + 7) + __shfl(c_l, qsrc + 7);

    int ncm = (qend - qbeg + 15) >> 4;                   // chunks of 16 edges per quarter
    ncm = max(ncm, __shfl_xor(ncm, 16));
    ncm = max(ncm, __shfl_xor(ncm, 32));                 // wave-uniform max

    // zero accu rows (deg-0 nodes never flushed)
#pragma unroll
    for (int i = 0; i < 8; ++i) {
        uint4 z; z.x = 0; z.y = 0; z.z = 0; z.w = 0;
        *((uint4*)accu + i * 64 + lane) = z;
    }

    // prestage the 32 XB rows into LDS (8 KB, coalesced)
#pragma unroll
    for (int j = 0; j < 8; ++j) {
        int fi = j * 64 + lane;                          // uint4 index 0..511
        int i  = fi >> 4;                                // row
        int k  = fi & 15;                                // uint4 within row
        uint4 v = *(const uint4*)(xtb32 + (size_t)(nbase + i) * 128 + 64 + (k << 2));
        *((uint4*)XBlds + fi) = v;
    }

    // ---- Phase A: quarter-wave edge streams, run-merged ----
    {
        float sl0 = 0.f, sl1 = 0.f, sl2 = 0.f, sl3 = 0.f;
        float sh0 = 0.f, sh1 = 0.f, sh2 = 0.f, sh3 = 0.f;
        int curnib = -1;

        auto flush = [&]() {
            uint4 o;
            o.x = pack_bf16_rne(sl0, sh0);
            o.y = pack_bf16_rne(sl1, sh1);
            o.z = pack_bf16_rne(sl2, sh2);
            o.w = pack_bf16_rne(sl3, sh3);
            *(uint4*)(accu + (curnib << 6) + (t << 2)) = o;
        };

        int pk = 0;
        { int idx = qbeg + t; if (idx < qend) pk = srowpk[idx]; }

        for (int c = 0; c < ncm; ++c) {
            const int rem = qend - qbeg - (c << 4);      // quarter-uniform remaining

            // prefetch next chunk's pk (hidden under this chunk's work)
            int pknext = 0;
            { int idx = qbeg + ((c + 1) << 4) + t; if (idx < qend) pknext = srowpk[idx]; }

            // batch-issue 16 XT gathers (1 KB per wave-instruction: 4 edges each)
            uint4 xt[16];
#pragma unroll
            for (int e = 0; e < 16; ++e) {
                int pv = __shfl(pk, q16 + e);            // unconditional shuffle
                uint4 z; z.x = 0; z.y = 0; z.z = 0; z.w = 0;
                xt[e] = z;
                if (e < rem)
                    xt[e] = *(const uint4*)(xtb32 + (size_t)(pv & ROW_MASK) * 128 + (t << 2));
            }

            // process 16 edges (4 in parallel across quarters per step)
#pragma unroll
            for (int e = 0; e < 16; ++e) {
                int pv = __shfl(pk, q16 + e);
                if (e < rem) {
                    int nib = pv >> 17;
                    uint4 xb = *(const uint4*)(XBlds + (nib << 6) + (t << 2));
                    float a0 = fmaxf(bflo(xt[e].x) + bflo(xb.x), 0.f);
                    float b0 = fmaxf(bfhi(xt[e].x) + bfhi(xb.x), 0.f);
                    float a1 = fmaxf(bflo(xt[e].y) + bflo(xb.y), 0.f);
                    float b1 = fmaxf(bfhi(xt[e].y) + bfhi(xb.y), 0.f);
                    float a2 = fmaxf(bflo(xt[e].z) + bflo(xb.z), 0.f);
                    float b2 = fmaxf(bfhi(xt[e].z) + bfhi(xb.z), 0.f);
                    float a3 = fmaxf(bflo(xt[e].w) + bflo(xb.w), 0.f);
                    float b3 = fmaxf(bfhi(xt[e].w) + bfhi(xb.w), 0.f);
                    if (nib != curnib) {
                        if (curnib >= 0) flush();
                        curnib = nib;
                        sl0 = a0; sh0 = b0; sl1 = a1; sh1 = b1;
                        sl2 = a2; sh2 = b2; sl3 = a3; sh3 = b3;
                    } else {
                        sl0 += a0; sh0 += b0; sl1 += a1; sh1 += b1;
                        sl2 += a2; sh2 += b2; sl3 += a3; sh3 += b3;
                    }
                }
            }
            pk = pknext;
        }
        if (curnib >= 0) flush();
    }

    // ---- Phase B: GEMMs + LN (wave-private LDS; per-wave DS ordering suffices) ----
    const float* px = x + (size_t)nc * D + half * 8;

    floatx16 acc[4];
#pragma unroll
    for (int tt = 0; tt < 4; ++tt) acc[tt] = (floatx16)0.0f;

#pragma unroll
    for (int s = 0; s < 16; ++s) {
        union { short8 v; uint32_t u[4]; } fa;
        const short8* bf;
        if (s < 8) {
            const int off = s * 16;
            float4 a0 = *(const float4*)(px + off);
            float4 a1 = *(const float4*)(px + off + 4);
            fa.u[0] = pack_bf16_rne(a0.x, a0.y); fa.u[1] = pack_bf16_rne(a0.z, a0.w);
            fa.u[2] = pack_bf16_rne(a1.x, a1.y); fa.u[3] = pack_bf16_rne(a1.z, a1.w);
            bf = wu1tf + (s * 4) * 64;
        } else {
            fa.v = *(const short8*)((const short*)accu + l31 * 128 + (s - 8) * 16 + half * 8);
            bf = wcf + ((s - 8) * 4) * 64;
        }
#pragma unroll
        for (int tt = 0; tt < 4; ++tt) {
            short8 wf = bf[tt * 64 + lane];
            acc[tt] = __builtin_amdgcn_mfma_f32_32x32x16_bf16(fa.v, wf, acc[tt], 0, 0, 0);
        }
    }

    float bu1[4], vbt[4];
#pragma unroll
    for (int tt = 0; tt < 4; ++tt) {
        bu1[tt] = b_u1[tt * 32 + l31];
        vbt[tt] = vb[tt * 32 + l31];
    }

#pragma unroll
    for (int r = 0; r < 16; ++r) {
        int m = (r & 3) + 8 * (r >> 2) + 4 * half;
        float dg = __shfl(dgv, m, 32);
#pragma unroll
        for (int tt = 0; tt < 4; ++tt) {
            float v = fmaxf(acc[tt][r] + bu1[tt] + dg * vbt[tt], 0.0f);
            hl[m * 136 + tt * 32 + l31] = (short)f32_to_bf16_rne(v);
        }
    }

    floatx16 acc2[4];
#pragma unroll
    for (int tt = 0; tt < 4; ++tt) acc2[tt] = (floatx16)0.0f;

#pragma unroll
    for (int s = 0; s < 8; ++s) {
        short8 af = *(const short8*)(hl + l31 * 136 + s * 16 + half * 8);
#pragma unroll
        for (int tt = 0; tt < 4; ++tt) {
            short8 wf = wu2f[(s * 4 + tt) * 64 + lane];
            acc2[tt] = __builtin_amdgcn_mfma_f32_32x32x16_bf16(af, wf, acc2[tt], 0, 0, 0);
        }
    }

    float g4[4], be4[4], bias2[4];
#pragma unroll
    for (int tt = 0; tt < 4; ++tt) {
        g4[tt]    = gamma[tt * 32 + l31];
        be4[tt]   = beta[tt * 32 + l31];
        bias2[tt] = b_u2[tt * 32 + l31];
    }

    // LN epilogue via LDS (fp32, two 16-row passes reusing hl) -> float4 stores.
    float* hf = (float*)hl;
#pragma unroll
    for (int p = 0; p < 2; ++p) {
#pragma unroll
        for (int rr = 0; rr < 8; ++rr) {
            int r = p * 8 + rr;
            float hv[4];
            float s1 = 0.0f, s2 = 0.0f;
#pragma unroll
            for (int tt = 0; tt < 4; ++tt) {
                hv[tt] = acc2[tt][r] + bias2[tt];
                s1 += hv[tt];
                s2 += hv[tt] * hv[tt];
            }
#pragma unroll
            for (int mask = 1; mask < 32; mask <<= 1) {
                s1 += __shfl_xor(s1, mask);
                s2 += __shfl_xor(s2, mask);
            }
            float mean = s1 * (1.0f / 128.0f);
            float var  = s2 * (1.0f / 128.0f) - mean * mean;
            float rs   = rsqrtf(var + EPS);
            int m = (r & 3) + 8 * (r >> 2) + 4 * half;
            int mrow = m - 16 * p;
#pragma unroll
            for (int tt = 0; tt < 4; ++tt)
                hf[mrow * 132 + tt * 32 + l31] = (hv[tt] - mean) * rs * g4[tt] + be4[tt];
        }
#pragma unroll
        for (int it = 0; it < 8; ++it) {
            int qq = it * 64 + lane;
            int r2 = qq >> 5;
            int c4 = qq & 31;
            int node = nbase + 16 * p + r2;
            float4 v = *(const float4*)(hf + r2 * 132 + c4 * 4);
            float4 xr = *(const float4*)(x + (size_t)node * D + c4 * 4);
            v.x += xr.x; v.y += xr.y; v.z += xr.z; v.w += xr.w;
            *(float4*)(out + (size_t)node * D + c4 * 4) = v;
        }
    }
}

// ---------- launch ----------
extern "C" void kernel_launch(void* const* d_in, const int* in_sizes, int n_in,
                              void* d_out, int out_size, void* d_ws, size_t ws_size,
                              hipStream_t stream) {
    const float* x     = (const float*)d_in[0];
    const int*   edge  = (const int*)d_in[1];
    const float* w_m1  = (const float*)d_in[2];
    const float* b_m1  = (const float*)d_in[3];
    const float* w_m2  = (const float*)d_in[4];
    const float* b_m2  = (const float*)d_in[5];
    const float* w_u1  = (const float*)d_in[6];
    const float* b_u1  = (const float*)d_in[7];
    const float* w_u2  = (const float*)d_in[8];
    const float* b_u2  = (const float*)d_in[9];
    const float* gamma = (const float*)d_in[10];
    const float* beta  = (const float*)d_in[11];
    float* out = (float*)d_out;

    char* ws = (char*)d_ws;
    size_t off = 0;
    auto alloc = [&](size_t bytes) { void* p = ws + off; off = (off + bytes + 15) & ~(size_t)15; return p; };

    unsigned short* xtb   = (unsigned short*)alloc((size_t)N_NODES * 256 * 2);  // XT | XB+b1
    unsigned short* wm1f  = (unsigned short*)alloc(256 * 128 * 2);
    unsigned short* wu1tf = (unsigned short*)alloc(128 * 128 * 2);
    unsigned short* wcf   = (unsigned short*)alloc(128 * 128 * 2);
    unsigned short* wu2f  = (unsigned short*)alloc(128 * 128 * 2);
    float* vb    = (float*)alloc(128 * 4);
    int* count   = (int*)alloc((size_t)N_NODES * 4 + 16);   // + gcur tail
    int* gcur    = count + N_NODES;
    int* base    = (int*)alloc((size_t)N_NODES * 4);
    int* rank    = (int*)alloc((size_t)N_EDGES * 4);
    int* srow    = (int*)alloc((size_t)N_EDGES * 4);

    const int* rowi = edge;            // edge_index[0]
    const int* coli = edge + N_EDGES;  // edge_index[1]
    const int NB = (N_NODES + SCAN_BS - 1) / SCAN_BS;  // 196 blocks

    (void)hipMemsetAsync(count, 0, (size_t)N_NODES * 4 + 16, stream);  // count + gcur

    // K1: all weight prep + destination histogram (+rank harvest)
    prep_hist<<<PREP_BLOCKS + HIST_BLOCKS, 256, 0, stream>>>(
        w_m1, w_u1, w_u2, w_m2, b_m2, wm1f, wu1tf, wu2f, wcf, vb, coli, count, rank);

    // K2: single-kernel scan
    scan_one<<<NB, SCAN_BS, 0, stream>>>(count, base, gcur);

    // K3: xform + atomic-free packed edge scatter fused
    xform_scatter<<<XF_BLOCKS + SC_BLOCKS, 64, 0, stream>>>(
        x, (const short8*)wm1f, b_m1, xtb, rowi, coli, rank, base, srow);

    // K4: fused aggregation + update (quarter-wave streams, LDS XB, batched gathers)
    upd_kernel<<<UPD_BLOCKS, 64, 0, stream>>>(
        x, (const uint32_t*)xtb, srow, base, count,
        (const short8*)wu1tf, (const short8*)wcf, (const short8*)wu2f,
        b_u1, vb, b_u2, gamma, beta, out);
}

// Round 3
// 254.639 us; speedup vs baseline: 1.0585x; 1.0067x over previous
//
#include <hip/hip_runtime.h>
#include <hip/hip_bf16.h>
#include <stdint.h>

#define N_NODES 100000
#define N_EDGES 600000
#define D 128
#define EPS 1e-5f
#define SCAN_BS 512
#define ROW_MASK 0x1FFFF

#define PREP_BLOCKS 321            // (82048+255)/256
#define HIST_BLOCKS 2344           // (N_EDGES+255)/256, 256-thread histogram blocks (K1)
#define XF_BLOCKS   3125           // N_NODES/32, 64-thread 1-wave xform blocks (K3)
#define SC_BLOCKS   2344           // (N_EDGES/4+63)/64, 64-thread x 4-edge scatter blocks (K3)
#define UPD_BLOCKS  3125           // N_NODES/32, 64-thread 1-wave blocks (K4)

typedef __attribute__((ext_vector_type(8))) short short8;
typedef __attribute__((ext_vector_type(16))) float floatx16;

// ---------- helpers ----------

__device__ __forceinline__ uint32_t pack_bf16_rne(float lo, float hi) {
    uint32_t ul = __builtin_bit_cast(uint32_t, lo);
    uint32_t uh = __builtin_bit_cast(uint32_t, hi);
    ul += 0x7fffu + ((ul >> 16) & 1u);
    uh += 0x7fffu + ((uh >> 16) & 1u);
    return (ul >> 16) | (uh & 0xffff0000u);
}

__device__ __forceinline__ unsigned short f32_to_bf16_rne(float f) {
    uint32_t u = __builtin_bit_cast(uint32_t, f);
    u += 0x7fffu + ((u >> 16) & 1u);
    return (unsigned short)(u >> 16);
}

__device__ __forceinline__ float bflo(uint32_t a) { return __builtin_bit_cast(float, a << 16); }
__device__ __forceinline__ float bfhi(uint32_t a) { return __builtin_bit_cast(float, a & 0xffff0000u); }

// ---------- K1: fused weight preprocessing + destination histogram (+rank) ----------
__global__ void prep_hist(const float* __restrict__ w_m1, const float* __restrict__ w_u1,
                          const float* __restrict__ w_u2, const float* __restrict__ w_m2,
                          const float* __restrict__ b_m2,
                          unsigned short* __restrict__ wm1f, unsigned short* __restrict__ wu1tf,
                          unsigned short* __restrict__ wu2f, unsigned short* __restrict__ wcf,
                          float* __restrict__ vb,
                          const int* __restrict__ col, int* __restrict__ count,
                          int* __restrict__ rank) {
    if (blockIdx.x >= PREP_BLOCKS) {
        int e = (blockIdx.x - PREP_BLOCKS) * 256 + threadIdx.x;
        if (e < N_EDGES) rank[e] = atomicAdd(&count[col[e]], 1);
        return;
    }
    int idx = blockIdx.x * 256 + threadIdx.x;
    if (idx < 32768) {
        int j = idx & 7, lane = (idx >> 3) & 63, t = (idx >> 9) & 3, s = idx >> 11;
        int kk = s * 16 + ((lane >> 5) << 3) + j;
        wm1f[idx] = f32_to_bf16_rne(w_m1[kk * 128 + t * 32 + (lane & 31)]);
    } else if (idx < 49152) {
        int ii = idx - 32768;
        int j = ii & 7, lane = (ii >> 3) & 63, t = (ii >> 9) & 3, s = ii >> 11;
        int kk = s * 16 + ((lane >> 5) << 3) + j;
        wu1tf[ii] = f32_to_bf16_rne(w_u1[kk * 128 + t * 32 + (lane & 31)]);
    } else if (idx < 65536) {
        int ii = idx - 49152;
        int j = ii & 7, lane = (ii >> 3) & 63, t = (ii >> 9) & 3, s = ii >> 11;
        int kk = s * 16 + ((lane >> 5) << 3) + j;
        wu2f[ii] = f32_to_bf16_rne(w_u2[kk * 128 + t * 32 + (lane & 31)]);
    } else if (idx < 81920) {
        int ii = idx - 65536;
        int j = ii & 7, lane = (ii >> 3) & 63, t = (ii >> 9) & 3, s = ii >> 11;
        int kk = s * 16 + ((lane >> 5) << 3) + j;
        int nn = t * 32 + (lane & 31);
        float acc = 0.0f;
        for (int q = 0; q < 128; ++q)
            acc += w_m2[kk * 128 + q] * w_u1[(128 + q) * 128 + nn];
        wcf[ii] = f32_to_bf16_rne(acc);
    } else if (idx < 82048) {
        int nn = idx - 81920;
        float acc = 0.0f;
        for (int q = 0; q < 128; ++q)
            acc += b_m2[q] * w_u1[(128 + q) * 128 + nn];
        vb[nn] = acc;
    }
}

// ---------- K2: single-kernel scan ----------
__global__ void scan_one(const int* __restrict__ count, int* __restrict__ base,
                         int* __restrict__ gcur) {
    __shared__ int tmp[SCAN_BS];
    __shared__ int bbase;
    int g = blockIdx.x * SCAN_BS + threadIdx.x;
    int v = (g < N_NODES) ? count[g] : 0;
    tmp[threadIdx.x] = v;
    __syncthreads();
    int acc = v;
#pragma unroll
    for (int off = 1; off < SCAN_BS; off <<= 1) {
        int add = (threadIdx.x >= off) ? tmp[threadIdx.x - off] : 0;
        __syncthreads();
        acc += add;
        tmp[threadIdx.x] = acc;
        __syncthreads();
    }
    if (threadIdx.x == SCAN_BS - 1) bbase = atomicAdd(gcur, acc);
    __syncthreads();
    if (g < N_NODES) base[g] = bbase + acc - v;
}

// ---------- K3: fused xform (XT|XB+b1 bf16 [node][256]) + atomic-free edge scatter ----------
__launch_bounds__(64, 4)
__global__ void xform_scatter(const float* __restrict__ x, const short8* __restrict__ w1f,
                              const float* __restrict__ b1, unsigned short* __restrict__ xtb,
                              const int* __restrict__ row, const int* __restrict__ col,
                              const int* __restrict__ rank, const int* __restrict__ base,
                              int* __restrict__ srow) {
    if (blockIdx.x >= XF_BLOCKS) {
        int e4 = (((blockIdx.x - XF_BLOCKS) * 64 + threadIdx.x) << 2);
        if (e4 < N_EDGES) {
            int4 r4 = *(const int4*)(row + e4);
            int4 c4 = *(const int4*)(col + e4);
            int4 k4 = *(const int4*)(rank + e4);
            srow[base[c4.x] + k4.x] = r4.x | ((c4.x & 31) << 17);
            srow[base[c4.y] + k4.y] = r4.y | ((c4.y & 31) << 17);
            srow[base[c4.z] + k4.z] = r4.z | ((c4.z & 31) << 17);
            srow[base[c4.w] + k4.w] = r4.w | ((c4.w & 31) << 17);
        }
        return;
    }

    __shared__ __align__(16) short h1[32 * 136];
    const int lane = threadIdx.x;
    const int l31  = lane & 31;
    const int half = lane >> 5;
    short* hl = h1;

    const int nbase = blockIdx.x * 32;          // 3125*32 == N_NODES exactly
    const int n = nbase + l31;
    const float* px = x + (size_t)n * D + half * 8;

    union { short8 v; uint32_t u[4]; } fa[8];
#pragma unroll
    for (int s = 0; s < 8; ++s) {
        const int off = s * 16;
        float4 a0 = *(const float4*)(px + off);
        float4 a1 = *(const float4*)(px + off + 4);
        fa[s].u[0] = pack_bf16_rne(a0.x, a0.y); fa[s].u[1] = pack_bf16_rne(a0.z, a0.w);
        fa[s].u[2] = pack_bf16_rne(a1.x, a1.y); fa[s].u[3] = pack_bf16_rne(a1.z, a1.w);
    }

#pragma unroll
    for (int p = 0; p < 2; ++p) {
        floatx16 acc[4];
#pragma unroll
        for (int t = 0; t < 4; ++t) acc[t] = (floatx16)0.0f;
#pragma unroll
        for (int s = 0; s < 8; ++s) {
#pragma unroll
            for (int t = 0; t < 4; ++t) {
                short8 wf = w1f[((p * 8 + s) * 4 + t) * 64 + lane];
                acc[t] = __builtin_amdgcn_mfma_f32_32x32x16_bf16(fa[s].v, wf, acc[t], 0, 0, 0);
            }
        }
#pragma unroll
        for (int t = 0; t < 4; ++t) {
            float bias = p ? b1[t * 32 + l31] : 0.0f;
#pragma unroll
            for (int r = 0; r < 16; ++r) {
                int m = (r & 3) + 8 * (r >> 2) + 4 * half;
                hl[m * 136 + t * 32 + l31] = (short)f32_to_bf16_rne(acc[t][r] + bias);
            }
        }
#pragma unroll
        for (int it = 0; it < 8; ++it) {
            int off = it * 512 + lane * 8;
            int r2 = off >> 7;
            int c2 = off & 127;
            short8 v = *(const short8*)(hl + r2 * 136 + c2);
            *(short8*)(xtb + (size_t)(nbase + r2) * 256 + p * 128 + c2) = v;
        }
    }
}

// ---------- K4: fused aggregation + update ----------
// 1-wave blocks, 32 nodes each. Phase A: quarter-wave edge streams, 16-edge chunks,
// UNCONDITIONAL gathers (invalid -> row 0, L1-hot) + sched_barrier(0) fence so the
// compiler cannot sink loads into the consume loop, explicit even/odd register
// double-buffer so chunk c+1's 16x1KB gathers are in flight while chunk c is consumed.
__launch_bounds__(64, 2)
__global__ void upd_kernel(const float* __restrict__ x, const uint32_t* __restrict__ xtb32,
                           const int* __restrict__ srowpk,
                           const int* __restrict__ base, const int* __restrict__ count,
                           const short8* __restrict__ wu1tf, const short8* __restrict__ wcf,
                           const short8* __restrict__ wu2f,
                           const float* __restrict__ b_u1, const float* __restrict__ vb,
                           const float* __restrict__ b_u2,
                           const float* __restrict__ gamma, const float* __restrict__ beta,
                           float* __restrict__ out) {
    __shared__ __align__(16) short h1[32 * 136];          // accu (phase A) / h + LN (phase B)
    __shared__ __align__(16) uint32_t XBlds[32 * 64];     // 32 XB rows, 8 KB
    const int lane = threadIdx.x;
    const int l31  = lane & 31;
    const int half = lane >> 5;
    const int t    = lane & 15;          // lane within quarter
    const int q16  = lane & 48;          // quarter * 16
    short* hl = h1;
    uint32_t* accu = (uint32_t*)hl;      // [32 nodes][64 dwords] bf16-packed

    const int nbase = blockIdx.x * 32;
    const int nc = nbase + l31;

    // per-node CSR info (lane-parallel)
    const int b_l = base[nc];
    const int c_l = count[nc];
    const float dgv = (float)c_l;

    // quarter q owns nodes [8q, 8q+8): contiguous CSR slice
    const int qsrc = q16 >> 1;                           // 8*q
    const int qbeg = __shfl(b_l, qsrc);
    const int qend = __shfl(b_l, qsrc + 7) + __shfl(c_l, qsrc + 7);
    const int rembase = qend - qbeg;

    int ncm = (rembase + 15) >> 4;                       // chunks of 16 edges per quarter
    ncm = max(ncm, __shfl_xor(ncm, 16));
    ncm = max(ncm, __shfl_xor(ncm, 32));                 // wave-uniform max

    // zero accu rows (deg-0 nodes never flushed)
#pragma unroll
    for (int i = 0; i < 8; ++i) {
        uint4 z; z.x = 0; z.y = 0; z.z = 0; z.w = 0;
        *((uint4*)accu + i * 64 + lane) = z;
    }

    // prestage the 32 XB rows into LDS (8 KB, coalesced)
#pragma unroll
    for (int j = 0; j < 8; ++j) {
        int fi = j * 64 + lane;                          // uint4 index 0..511
        int i  = fi >> 4;                                // row
        int k  = fi & 15;                                // uint4 within row
        uint4 v = *(const uint4*)(xtb32 + (size_t)(nbase + i) * 128 + 64 + (k << 2));
        *((uint4*)XBlds + fi) = v;
    }

    // ---- Phase A: double-buffered gather pipeline ----
    {
        float sl0 = 0.f, sl1 = 0.f, sl2 = 0.f, sl3 = 0.f;
        float sh0 = 0.f, sh1 = 0.f, sh2 = 0.f, sh3 = 0.f;
        int curnib = -1;

        auto flush = [&]() {
            uint4 o;
            o.x = pack_bf16_rne(sl0, sh0);
            o.y = pack_bf16_rne(sl1, sh1);
            o.z = pack_bf16_rne(sl2, sh2);
            o.w = pack_bf16_rne(sl3, sh3);
            *(uint4*)(accu + (curnib << 6) + (t << 2)) = o;
        };

        // clamped pk load for chunk c (always in-bounds; validity handled later)
        auto ldpk = [&](int c) -> int {
            int idx = qbeg + (c << 4) + t;
            return srowpk[min(idx, N_EDGES - 1)];
        };

        // issue 16 unconditional gathers for chunk c (invalid edges -> row 0, L1-hot)
        auto issue = [&](int pkv, int c, uint4* xt, int* pv) {
#pragma unroll
            for (int e = 0; e < 16; ++e) {
                int p = __shfl(pkv, q16 + e);
                if ((c << 4) + e >= rembase) p = 0;      // quarter-uniform predicate
                pv[e] = p;
                xt[e] = *(const uint4*)(xtb32 + (size_t)(p & ROW_MASK) * 128 + (t << 2));
            }
        };

        auto consume = [&](const uint4* xt, const int* pv, int rem) {
#pragma unroll
            for (int e = 0; e < 16; ++e) {
                if (e < rem) {
                    int nib = pv[e] >> 17;
                    uint4 xb = *(const uint4*)(XBlds + (nib << 6) + (t << 2));
                    float a0 = fmaxf(bflo(xt[e].x) + bflo(xb.x), 0.f);
                    float b0 = fmaxf(bfhi(xt[e].x) + bfhi(xb.x), 0.f);
                    float a1 = fmaxf(bflo(xt[e].y) + bflo(xb.y), 0.f);
                    float b1 = fmaxf(bfhi(xt[e].y) + bfhi(xb.y), 0.f);
                    float a2 = fmaxf(bflo(xt[e].z) + bflo(xb.z), 0.f);
                    float b2 = fmaxf(bfhi(xt[e].z) + bfhi(xb.z), 0.f);
                    float a3 = fmaxf(bflo(xt[e].w) + bflo(xb.w), 0.f);
                    float b3 = fmaxf(bfhi(xt[e].w) + bfhi(xb.w), 0.f);
                    if (nib != curnib) {
                        if (curnib >= 0) flush();
                        curnib = nib;
                        sl0 = a0; sh0 = b0; sl1 = a1; sh1 = b1;
                        sl2 = a2; sh2 = b2; sl3 = a3; sh3 = b3;
                    } else {
                        sl0 += a0; sh0 += b0; sl1 += a1; sh1 += b1;
                        sl2 += a2; sh2 += b2; sl3 += a3; sh3 += b3;
                    }
                }
            }
        };

        uint4 xtA[16], xtB[16];
        int pvA[16], pvB[16];

        int pkc = ldpk(0);
        issue(pkc, 0, xtA, pvA);                         // chunk 0 in flight
        int pkn = ldpk(1);

        for (int cc = 0; cc < ncm; cc += 2) {
            issue(pkn, cc + 1, xtB, pvB);                // chunk cc+1 in flight
            pkc = ldpk(cc + 2);                          // pk prefetch (1 iter ahead)
            __builtin_amdgcn_sched_barrier(0);
            consume(xtA, pvA, rembase - (cc << 4));      // chunk cc

            issue(pkc, cc + 2, xtA, pvA);                // chunk cc+2 in flight
            pkn = ldpk(cc + 3);
            __builtin_amdgcn_sched_barrier(0);
            consume(xtB, pvB, rembase - ((cc + 1) << 4)); // chunk cc+1
        }
        if (curnib >= 0) flush();
    }

    // ---- Phase B: GEMMs + LN (wave-private LDS; per-wave DS ordering suffices) ----
    const float* px = x + (size_t)nc * D + half * 8;

    floatx16 acc[4];
#pragma unroll
    for (int tt = 0; tt < 4; ++tt) acc[tt] = (floatx16)0.0f;

#pragma unroll
    for (int s = 0; s < 16; ++s) {
        union { short8 v; uint32_t u[4]; } fa;
        const short8* bf;
        if (s < 8) {
            const int off = s * 16;
            float4 a0 = *(const float4*)(px + off);
            float4 a1 = *(const float4*)(px + off + 4);
            fa.u[0] = pack_bf16_rne(a0.x, a0.y); fa.u[1] = pack_bf16_rne(a0.z, a0.w);
            fa.u[2] = pack_bf16_rne(a1.x, a1.y); fa.u[3] = pack_bf16_rne(a1.z, a1.w);
            bf = wu1tf + (s * 4) * 64;
        } else {
            fa.v = *(const short8*)((const short*)accu + l31 * 128 + (s - 8) * 16 + half * 8);
            bf = wcf + ((s - 8) * 4) * 64;
        }
#pragma unroll
        for (int tt = 0; tt < 4; ++tt) {
            short8 wf = bf[tt * 64 + lane];
            acc[tt] = __builtin_amdgcn_mfma_f32_32x32x16_bf16(fa.v, wf, acc[tt], 0, 0, 0);
        }
    }

    float bu1[4], vbt[4];
#pragma unroll
    for (int tt = 0; tt < 4; ++tt) {
        bu1[tt] = b_u1[tt * 32 + l31];
        vbt[tt] = vb[tt * 32 + l31];
    }

#pragma unroll
    for (int r = 0; r < 16; ++r) {
        int m = (r & 3) + 8 * (r >> 2) + 4 * half;
        float dg = __shfl(dgv, m, 32);
#pragma unroll
        for (int tt = 0; tt < 4; ++tt) {
            float v = fmaxf(acc[tt][r] + bu1[tt] + dg * vbt[tt], 0.0f);
            hl[m * 136 + tt * 32 + l31] = (short)f32_to_bf16_rne(v);
        }
    }

    floatx16 acc2[4];
#pragma unroll
    for (int tt = 0; tt < 4; ++tt) acc2[tt] = (floatx16)0.0f;

#pragma unroll
    for (int s = 0; s < 8; ++s) {
        short8 af = *(const short8*)(hl + l31 * 136 + s * 16 + half * 8);
#pragma unroll
        for (int tt = 0; tt < 4; ++tt) {
            short8 wf = wu2f[(s * 4 + tt) * 64 + lane];
            acc2[tt] = __builtin_amdgcn_mfma_f32_32x32x16_bf16(af, wf, acc2[tt], 0, 0, 0);
        }
    }

    float g4[4], be4[4], bias2[4];
#pragma unroll
    for (int tt = 0; tt < 4; ++tt) {
        g4[tt]    = gamma[tt * 32 + l31];
        be4[tt]   = beta[tt * 32 + l31];
        bias2[tt] = b_u2[tt * 32 + l31];
    }

    // LN epilogue via LDS (fp32, two 16-row passes reusing hl) -> float4 stores.
    float* hf = (float*)hl;
#pragma unroll
    for (int p = 0; p < 2; ++p) {
#pragma unroll
        for (int rr = 0; rr < 8; ++rr) {
            int r = p * 8 + rr;
            float hv[4];
            float s1 = 0.0f, s2 = 0.0f;
#pragma unroll
            for (int tt = 0; tt < 4; ++tt) {
                hv[tt] = acc2[tt][r] + bias2[tt];
                s1 += hv[tt];
                s2 += hv[tt] * hv[tt];
            }
#pragma unroll
            for (int mask = 1; mask < 32; mask <<= 1) {
                s1 += __shfl_xor(s1, mask);
                s2 += __shfl_xor(s2, mask);
            }
            float mean = s1 * (1.0f / 128.0f);
            float var  = s2 * (1.0f / 128.0f) - mean * mean;
            float rs   = rsqrtf(var + EPS);
            int m = (r & 3) + 8 * (r >> 2) + 4 * half;
            int mrow = m - 16 * p;
#pragma unroll
            for (int tt = 0; tt < 4; ++tt)
                hf[mrow * 132 + tt * 32 + l31] = (hv[tt] - mean) * rs * g4[tt] + be4[tt];
        }
#pragma unroll
        for (int it = 0; it < 8; ++it) {
            int qq = it * 64 + lane;
            int r2 = qq >> 5;
            int c4 = qq & 31;
            int node = nbase + 16 * p + r2;
            float4 v = *(const float4*)(hf + r2 * 132 + c4 * 4);
            float4 xr = *(const float4*)(x + (size_t)node * D + c4 * 4);
            v.x += xr.x; v.y += xr.y; v.z += xr.z; v.w += xr.w;
            *(float4*)(out + (size_t)node * D + c4 * 4) = v;
        }
    }
}

// ---------- launch ----------
extern "C" void kernel_launch(void* const* d_in, const int* in_sizes, int n_in,
                              void* d_out, int out_size, void* d_ws, size_t ws_size,
                              hipStream_t stream) {
    const float* x     = (const float*)d_in[0];
    const int*   edge  = (const int*)d_in[1];
    const float* w_m1  = (const float*)d_in[2];
    const float* b_m1  = (const float*)d_in[3];
    const float* w_m2  = (const float*)d_in[4];
    const float* b_m2  = (const float*)d_in[5];
    const float* w_u1  = (const float*)d_in[6];
    const float* b_u1  = (const float*)d_in[7];
    const float* w_u2  = (const float*)d_in[8];
    const float* b_u2  = (const float*)d_in[9];
    const float* gamma = (const float*)d_in[10];
    const float* beta  = (const float*)d_in[11];
    float* out = (float*)d_out;

    char* ws = (char*)d_ws;
    size_t off = 0;
    auto alloc = [&](size_t bytes) { void* p = ws + off; off = (off + bytes + 15) & ~(size_t)15; return p; };

    unsigned short* xtb   = (unsigned short*)alloc((size_t)N_NODES * 256 * 2);  // XT | XB+b1
    unsigned short* wm1f  = (unsigned short*)alloc(256 * 128 * 2);
    unsigned short* wu1tf = (unsigned short*)alloc(128 * 128 * 2);
    unsigned short* wcf   = (unsigned short*)alloc(128 * 128 * 2);
    unsigned short* wu2f  = (unsigned short*)alloc(128 * 128 * 2);
    float* vb    = (float*)alloc(128 * 4);
    int* count   = (int*)alloc((size_t)N_NODES * 4 + 16);   // + gcur tail
    int* gcur    = count + N_NODES;
    int* base    = (int*)alloc((size_t)N_NODES * 4);
    int* rank    = (int*)alloc((size_t)N_EDGES * 4);
    int* srow    = (int*)alloc((size_t)N_EDGES * 4);

    const int* rowi = edge;            // edge_index[0]
    const int* coli = edge + N_EDGES;  // edge_index[1]
    const int NB = (N_NODES + SCAN_BS - 1) / SCAN_BS;  // 196 blocks

    (void)hipMemsetAsync(count, 0, (size_t)N_NODES * 4 + 16, stream);  // count + gcur

    // K1: all weight prep + destination histogram (+rank harvest)
    prep_hist<<<PREP_BLOCKS + HIST_BLOCKS, 256, 0, stream>>>(
        w_m1, w_u1, w_u2, w_m2, b_m2, wm1f, wu1tf, wu2f, wcf, vb, coli, count, rank);

    // K2: single-kernel scan
    scan_one<<<NB, SCAN_BS, 0, stream>>>(count, base, gcur);

    // K3: xform + atomic-free packed edge scatter fused
    xform_scatter<<<XF_BLOCKS + SC_BLOCKS, 64, 0, stream>>>(
        x, (const short8*)wm1f, b_m1, xtb, rowi, coli, rank, base, srow);

    // K4: fused aggregation + update (forced-deep gather pipeline)
    upd_kernel<<<UPD_BLOCKS, 64, 0, stream>>>(
        x, (const uint32_t*)xtb, srow, base, count,
        (const short8*)wu1tf, (const short8*)wcf, (const short8*)wu2f,
        b_u1, vb, b_u2, gamma, beta, out);
}